// Round 5
// baseline (145.742 us; speedup 1.0000x reference)
//
#include <hip/hip_runtime.h>
#include <math.h>

#define S_LEN 512
#define BATCH 16
#define DIN   512
#define DF    512
#define NMIX  10
#define NCHAR 1024
#define DCTX  256
#define M_ROWS (S_LEN*BATCH)   // 8192

// d_out layout (tuple flattened in return order)
#define OFF_CTXOUT 0
#define OFF_ATTN   (S_LEN*BATCH*DCTX)
#define OFF_MEANS  (OFF_ATTN + S_LEN*BATCH*NCHAR)
#define OFF_VARS   (OFF_MEANS + S_LEN*BATCH*NMIX)
#define OFF_WTS    (OFF_VARS  + S_LEN*BATCH*NMIX)

// scratch layout in d_ws (byte offsets)
#define WS_XH    0            // f16  8 MB   (8192x512)
#define WS_W1T   (8u<<20)     // f16  512 KB (512x512, [n][k] TRANSPOSED)
#define WS_W2T   (9u<<20)     // f32  64 KB  (32x512 padded)
#define WS_HH    (10u<<20)    // f16  8 MB
#define WS_DM    (26u<<20)    // f32  320 KB delta-means, chain-major [b][k][s]

#define NX4     1048576       // X float4 count
#define CVT_BLOCKS (NX4/256)  // 4096
#define W1T_BLOCKS 64
#define W2T_BLOCKS 64

typedef float    f32x16 __attribute__((ext_vector_type(16)));
typedef float    f32x4v __attribute__((ext_vector_type(4)));
typedef _Float16 f16x8  __attribute__((ext_vector_type(8)));

__device__ __forceinline__ unsigned short f2h(float x) {
    union { _Float16 h; unsigned short u; } cv;
    cv.h = (_Float16)x;
    return cv.u;
}
__device__ __forceinline__ ushort4 cvt4(float4 v) {
    ushort4 o; o.x = f2h(v.x); o.y = f2h(v.y); o.z = f2h(v.z); o.w = f2h(v.w);
    return o;
}
__device__ __forceinline__ void nt_store4(float* p, float a, float b, float c, float d) {
    f32x4v v; v.x = a; v.y = b; v.z = c; v.w = d;
    __builtin_nontemporal_store(v, (f32x4v*)p);
}

// ---------------------------------------------------------------------------
// Kernel 0: convert X -> f16; W1 -> f16 TRANSPOSED [n][k]; W2^T fp32.
// ---------------------------------------------------------------------------
__global__ __launch_bounds__(256) void convert_kernel(
    const float* __restrict__ X, const float* __restrict__ W1,
    const float* __restrict__ W2,
    unsigned short* __restrict__ Xh, unsigned short* __restrict__ W1T,
    float* __restrict__ W2T)
{
    const int bid = blockIdx.x;
    const int tid = threadIdx.x;
    if (bid < CVT_BLOCKS) {
        const int i4 = bid*256 + tid;
        ((ushort4*)Xh)[i4] = cvt4(((const float4*)X)[i4]);
    } else if (bid < CVT_BLOCKS + W1T_BLOCKS) {
        __shared__ unsigned short tile[64*68];
        const int b2 = bid - CVT_BLOCKS;
        const int k0 = (b2 >> 3) * 64, n0 = (b2 & 7) * 64;
        #pragma unroll
        for (int q = 0; q < 4; q++) {
            const int r = q*16 + (tid >> 4);
            const int c = (tid & 15) * 4;
            float4 v = *(const float4*)(W1 + (size_t)(k0+r)*DF + n0 + c);
            *(ushort4*)(tile + r*68 + c) = cvt4(v);
        }
        __syncthreads();
        #pragma unroll
        for (int q = 0; q < 4; q++) {
            const int n  = q*16 + (tid >> 4);
            const int kq = (tid & 15) * 4;
            ushort4 o;
            o.x = tile[(kq+0)*68 + n];
            o.y = tile[(kq+1)*68 + n];
            o.z = tile[(kq+2)*68 + n];
            o.w = tile[(kq+3)*68 + n];
            *(ushort4*)(W1T + (size_t)(n0+n)*DIN + k0 + kq) = o;
        }
    } else {
        const int idx = (bid - CVT_BLOCKS - W1T_BLOCKS)*256 + tid;
        if (idx < 512*32) {
            const int j = idx >> 9, k = idx & 511;
            W2T[idx] = (j < 30) ? W2[k*30 + j] : 0.f;
        }
    }
}

// ---------------------------------------------------------------------------
// Kernel 1: GEMM1 via f16 MFMA 32x32x16, 64x64 tiles, k-major operands.
// (round-0-verified structure; 256-thread blocks keep full register budget)
// ---------------------------------------------------------------------------
__global__ __launch_bounds__(256) void gemm1_kernel(
    const unsigned short* __restrict__ Xh, const unsigned short* __restrict__ W1T,
    const float* __restrict__ b1, unsigned short* __restrict__ Hh)
{
    __shared__ __align__(16) unsigned short As[64*72];
    __shared__ __align__(16) unsigned short Bs[64*72];
    const int row0 = (blockIdx.x >> 3) * 64;
    const int n0   = (blockIdx.x & 7)  * 64;
    const int tid  = threadIdx.x;
    const int lane = tid & 63, w = tid >> 6;
    const int wr = (w >> 1) * 32, wc = (w & 1) * 32;
    const int m  = lane & 31,  g  = lane >> 5;
    const int sa = tid >> 2,   ka = (tid & 3) * 16;

    f32x16 acc = {};
    const unsigned short* aptr = Xh  + (size_t)(row0+sa)*DIN + ka;
    const unsigned short* bptr = W1T + (size_t)(n0 +sa)*DIN + ka;

    for (int kt = 0; kt < DIN; kt += 64) {
        uint4 av0 = *(const uint4*)(aptr + kt);
        uint4 av1 = *(const uint4*)(aptr + kt + 8);
        uint4 bv0 = *(const uint4*)(bptr + kt);
        uint4 bv1 = *(const uint4*)(bptr + kt + 8);
        __syncthreads();
        *(uint4*)(As + sa*72 + ka)     = av0;
        *(uint4*)(As + sa*72 + ka + 8) = av1;
        *(uint4*)(Bs + sa*72 + ka)     = bv0;
        *(uint4*)(Bs + sa*72 + ka + 8) = bv1;
        __syncthreads();
        #pragma unroll
        for (int ks = 0; ks < 64; ks += 16) {
            f16x8 af = *(const f16x8*)(As + (wr+m)*72 + ks + g*8);
            f16x8 bf = *(const f16x8*)(Bs + (wc+m)*72 + ks + g*8);
            acc = __builtin_amdgcn_mfma_f32_32x32x16_f16(af, bf, acc, 0, 0, 0);
        }
    }
    const int ncol = n0 + wc + m;
    const float bb = b1[ncol];
    #pragma unroll
    for (int r = 0; r < 16; r++) {
        const int rowloc = (r & 3) + 8*(r >> 2) + 4*g;
        const int row = row0 + wr + rowloc;
        float v = acc[r] + bb;
        v = v > 0.f ? v : 0.01f * v;
        Hh[(size_t)row*DF + ncol] = f2h(v);
    }
}

// ---------------------------------------------------------------------------
// Kernel 2: GEMM2 (8192x30, K=512); LDS-staged H, broadcast W2T reads.
// delta-means written chain-major [b][k][s] for the fused scan (round-2-
// verified path); vars/wts straight to output.
// ---------------------------------------------------------------------------
__global__ __launch_bounds__(256) void gemm2_kernel(
    const unsigned short* __restrict__ Hh, const float* __restrict__ W2T,
    const float* __restrict__ b2,
    float* __restrict__ dm_ws, float* __restrict__ dvars, float* __restrict__ dwts)
{
    __shared__ __align__(16) unsigned short Hs[32*520];
    const int tid = threadIdx.x;
    const int r0  = blockIdx.x * 32;
    {
        const uint4* src = (const uint4*)(Hh + (size_t)r0*DF);
        #pragma unroll
        for (int i = 0; i < 8; i++) {
            int u   = tid + i*256;
            int row = u >> 6;
            int col = (u & 63) * 8;
            *(uint4*)(Hs + row*520 + col) = src[u];
        }
    }
    __syncthreads();

    const int r  = tid & 31;
    const int j0 = tid >> 5;
    const unsigned short* hrow = Hs + r*520;
    float acc[4] = {0.f, 0.f, 0.f, 0.f};

    for (int k0 = 0; k0 < DF; k0 += 8) {
        union { uint4 u; _Float16 h[8]; } hv;
        hv.u = *(const uint4*)(hrow + k0);
        float wv[4][8];
        #pragma unroll
        for (int q = 0; q < 4; q++) {
            *(float4*)(wv[q])     = *(const float4*)(W2T + (size_t)(j0 + q*8)*DF + k0);
            *(float4*)(wv[q] + 4) = *(const float4*)(W2T + (size_t)(j0 + q*8)*DF + k0 + 4);
        }
        #pragma unroll
        for (int i = 0; i < 8; i++) {
            float hf = (float)hv.h[i];
            acc[0] = fmaf(hf, wv[0][i], acc[0]);
            acc[1] = fmaf(hf, wv[1][i], acc[1]);
            acc[2] = fmaf(hf, wv[2][i], acc[2]);
            acc[3] = fmaf(hf, wv[3][i], acc[3]);
        }
    }
    const int row = r0 + r;
    #pragma unroll
    for (int q = 0; q < 4; q++) {
        const int j = j0 + q*8;
        if (j >= 30) continue;
        float dot = acc[q] + b2[j];
        float sp  = fmaxf(dot, 0.f) + log1pf(__expf(-fabsf(dot)));
        if (j < 10) {
            const int bb = row & (BATCH-1), s = row >> 4;
            dm_ws[((size_t)bb*NMIX + j)*S_LEN + s] = sp * (1.f/25.f);
        }
        else if (j < 20)  dvars[row*NMIX + (j-10)] = fminf(fmaxf(sp, 0.01f), 100.f);
        else              dwts [row*NMIX + (j-20)] = sp;
    }
}

// ---------------------------------------------------------------------------
// Kernel 3: fused scan + means + attention weights + attended contexts.
// 256 threads (4 waves) — NOT 512: rounds 2/3 measured that 512-thread
// blocks get a 56-VGPR cap here and spill ~85 MB of scratch.
// Grid: (batch=16) x (16 s-tiles of 32 rows) = 256 blocks.
// Per block: lane-parallel prefix sum for the carry + 32-wide window scan,
// local reach bound (no atomics), then per-64-char chunk: attn f32 out +
// f16 A-tile + ctx staged (f32->f16, transposed) + MFMA.  attnh round-trip
// and standalone scan/attn/ctx dispatches eliminated.
// ---------------------------------------------------------------------------
__global__ __launch_bounds__(256) void fused_kernel(
    const float* __restrict__ dm_ws, const float* __restrict__ init_means,
    const float* __restrict__ vars_g, const float* __restrict__ wts_g,
    const float* __restrict__ ctx,
    float* __restrict__ means_out, float* __restrict__ attn_out,
    float* __restrict__ ctxout)
{
    __shared__ float mlds[320];
    __shared__ float vlds[320];
    __shared__ float wlds[320];
    __shared__ float redbuf[4];
    __shared__ __align__(16) unsigned short As[32*72];     //  4.5 KB
    __shared__ __align__(16) unsigned short Bs[256*72];    // 36.0 KB

    const int bid = blockIdx.x;
    const int b   = bid >> 4;          // batch
    const int s0  = (bid & 15) * 32;   // first row of tile
    const int tid = threadIdx.x;
    const int lane = tid & 63, w = tid >> 6;   // 4 waves
    const int m = lane & 31, g = lane >> 5;

    // ---- carry (parallel sum over [0,s0)) + 32-window scan, per chain ----
    for (int k = w; k < NMIX; k += 4) {
        const float* chain = dm_ws + ((size_t)b*NMIX + k)*S_LEN;
        float part = 0.f;
        for (int s = lane; s < s0; s += 64) part += chain[s];
        #pragma unroll
        for (int d = 32; d >= 1; d >>= 1) part += __shfl_xor(part, d, 64);
        const float carry = init_means[b*NMIX + k] + part;
        float v = (lane < 32) ? chain[s0 + lane] : 0.f;
        #pragma unroll
        for (int d = 1; d < 32; d <<= 1) {
            float t = __shfl_up(v, d, 64);
            if (lane >= d) v += t;
        }
        if (lane < 32) mlds[lane*NMIX + k] = carry + v;
    }
    for (int idx = tid; idx < 320; idx += 256) {
        const int s = idx / NMIX, k = idx - s*NMIX;
        const int row = (s0 + s)*BATCH + b;
        vlds[idx] = vars_g[row*NMIX + k];
        wlds[idx] = wts_g [row*NMIX + k];
    }
    __syncthreads();

    // ---- means output + local reach bound (no atomics) ----
    float reach = 0.f;
    for (int idx = tid; idx < 320; idx += 256) {
        const int s = idx / NMIX, k = idx - s*NMIX;
        means_out[((s0 + s)*BATCH + b)*NMIX + k] = mlds[idx];
        reach = fmaxf(reach, mlds[idx] + 4.8f * rsqrtf(vlds[idx]));
    }
    #pragma unroll
    for (int d = 32; d >= 1; d >>= 1) reach = fmaxf(reach, __shfl_xor(reach, d, 64));
    if (lane == 0) redbuf[w] = reach;
    __syncthreads();
    const float rmax = fmaxf(fmaxf(redbuf[0], redbuf[1]),
                             fmaxf(redbuf[2], redbuf[3]));
    const int kmax = min(NCHAR, (((int)rmax) + 64) & ~63);

    // ---- per-thread row params (row r fixed across chunks) ----
    const int r  = tid >> 3;       // 0..31
    const int c0 = (tid & 7) * 8;  // 8 chars per thread per 64-chunk
    float mr[NMIX], vr[NMIX], wr_[NMIX];
    #pragma unroll
    for (int k = 0; k < NMIX; k++) {
        mr[k]  = mlds[r*NMIX + k];
        vr[k]  = vlds[r*NMIX + k];
        wr_[k] = wlds[r*NMIX + k];
    }
    const size_t arow = (size_t)((s0 + r)*BATCH + b) * NCHAR;

    // ctx staging ids: thread covers (char-row tb, dctx seg dseg*64..+63)
    const int tb = tid & 63, dseg = tid >> 6;
    const float* cbase = ctx + (size_t)b*DCTX + dseg*64;

    f32x16 acc0 = {}, acc1 = {};
    for (int kt = 0; kt < kmax; kt += 64) {
        // attention weights for chars kt+c0 .. +7 of row r
        float o[8];
        #pragma unroll
        for (int i = 0; i < 8; i++) {
            const float t = (float)(kt + c0 + i);
            float sum = 0.f;
            #pragma unroll
            for (int k = 0; k < NMIX; k++) {
                float d = t - mr[k];
                sum += wr_[k] * __expf(-d*d*vr[k]);
            }
            o[i] = sum;
        }
        __syncthreads();   // previous chunk's MFMA reads done
        nt_store4(attn_out + arow + kt + c0,     o[0], o[1], o[2], o[3]);
        nt_store4(attn_out + arow + kt + c0 + 4, o[4], o[5], o[6], o[7]);
        {
            ushort4 h0, h1;
            h0.x = f2h(o[0]); h0.y = f2h(o[1]); h0.z = f2h(o[2]); h0.w = f2h(o[3]);
            h1.x = f2h(o[4]); h1.y = f2h(o[5]); h1.z = f2h(o[6]); h1.w = f2h(o[7]);
            *(ushort4*)(As + r*72 + c0)     = h0;
            *(ushort4*)(As + r*72 + c0 + 4) = h1;
        }
        {
            const float* p = cbase + (size_t)(kt + tb)*(BATCH*DCTX);
            #pragma unroll
            for (int e = 0; e < 4; e++) {
                float4 f0 = *(const float4*)(p + e*16);
                float4 f1 = *(const float4*)(p + e*16 + 4);
                float4 f2 = *(const float4*)(p + e*16 + 8);
                float4 f3 = *(const float4*)(p + e*16 + 12);
                ushort4 h0 = cvt4(f0), h1 = cvt4(f1), h2 = cvt4(f2), h3 = cvt4(f3);
                const int db = dseg*64 + e*16;
                Bs[(db + 0)*72 + tb] = h0.x;  Bs[(db + 1)*72 + tb] = h0.y;
                Bs[(db + 2)*72 + tb] = h0.z;  Bs[(db + 3)*72 + tb] = h0.w;
                Bs[(db + 4)*72 + tb] = h1.x;  Bs[(db + 5)*72 + tb] = h1.y;
                Bs[(db + 6)*72 + tb] = h1.z;  Bs[(db + 7)*72 + tb] = h1.w;
                Bs[(db + 8)*72 + tb] = h2.x;  Bs[(db + 9)*72 + tb] = h2.y;
                Bs[(db +10)*72 + tb] = h2.z;  Bs[(db +11)*72 + tb] = h2.w;
                Bs[(db +12)*72 + tb] = h3.x;  Bs[(db +13)*72 + tb] = h3.y;
                Bs[(db +14)*72 + tb] = h3.z;  Bs[(db +15)*72 + tb] = h3.w;
            }
        }
        __syncthreads();
        #pragma unroll
        for (int ks = 0; ks < 64; ks += 16) {
            f16x8 af  = *(const f16x8*)(As + m*72 + ks + g*8);
            f16x8 bf0 = *(const f16x8*)(Bs + (w*64 + m)*72      + ks + g*8);
            f16x8 bf1 = *(const f16x8*)(Bs + (w*64 + 32 + m)*72 + ks + g*8);
            acc0 = __builtin_amdgcn_mfma_f32_32x32x16_f16(af, bf0, acc0, 0, 0, 0);
            acc1 = __builtin_amdgcn_mfma_f32_32x32x16_f16(af, bf1, acc1, 0, 0, 0);
        }
    }
    // zero tail of attention output
    for (int t = kmax + c0; t < NCHAR; t += 64) {
        nt_store4(attn_out + arow + t,     0.f, 0.f, 0.f, 0.f);
        nt_store4(attn_out + arow + t + 4, 0.f, 0.f, 0.f, 0.f);
    }

    // attended-context epilogue: wave w owns dctx cols w*64+m and w*64+32+m
    #pragma unroll
    for (int rr = 0; rr < 16; rr++) {
        const int rowloc = (rr & 3) + 8*(rr >> 2) + 4*g;
        const int s = s0 + rowloc;
        float* op = ctxout + ((size_t)s*BATCH + b)*DCTX + w*64 + m;
        __builtin_nontemporal_store(acc0[rr], op);
        __builtin_nontemporal_store(acc1[rr], op + 32);
    }
}

// ---------------------------------------------------------------------------
extern "C" void kernel_launch(void* const* d_in, const int* in_sizes, int n_in,
                              void* d_out, int out_size, void* d_ws, size_t ws_size,
                              hipStream_t stream)
{
    const float* X     = (const float*)d_in[0];
    const float* ctx   = (const float*)d_in[1];
    const float* initm = (const float*)d_in[2];
    const float* W1    = (const float*)d_in[3];
    const float* b1    = (const float*)d_in[4];
    const float* W2    = (const float*)d_in[5];
    const float* b2    = (const float*)d_in[6];

    float* out      = (float*)d_out;
    float* out_ctx  = out + OFF_CTXOUT;
    float* out_attn = out + OFF_ATTN;
    float* out_mean = out + OFF_MEANS;
    float* out_var  = out + OFF_VARS;
    float* out_wts  = out + OFF_WTS;

    char* ws = (char*)d_ws;
    unsigned short* Xh   = (unsigned short*)(ws + WS_XH);
    unsigned short* W1T  = (unsigned short*)(ws + WS_W1T);
    float*          W2T  = (float*)         (ws + WS_W2T);
    unsigned short* Hh   = (unsigned short*)(ws + WS_HH);
    float*          dmws = (float*)         (ws + WS_DM);

    convert_kernel<<<CVT_BLOCKS + W1T_BLOCKS + W2T_BLOCKS, 256, 0, stream>>>(
        X, W1, W2, Xh, W1T, W2T);
    gemm1_kernel<<<(M_ROWS/64)*(DF/64), 256, 0, stream>>>(Xh, W1T, b1, Hh);
    gemm2_kernel<<<M_ROWS/32, 256, 0, stream>>>(Hh, W2T, b2, dmws, out_var, out_wts);
    fused_kernel<<<BATCH*16, 256, 0, stream>>>(dmws, initm, out_var, out_wts, ctx,
                                               out_mean, out_attn, out_ctx);
}

// Round 6
// 144.546 us; speedup vs baseline: 1.0083x; 1.0083x over previous
//
#include <hip/hip_runtime.h>
#include <math.h>

#define S_LEN 512
#define BATCH 16
#define DIN   512
#define DF    512
#define NMIX  10
#define NCHAR 1024
#define DCTX  256
#define M_ROWS (S_LEN*BATCH)   // 8192

// d_out layout (tuple flattened in return order)
#define OFF_CTXOUT 0
#define OFF_ATTN   (S_LEN*BATCH*DCTX)
#define OFF_MEANS  (OFF_ATTN + S_LEN*BATCH*NCHAR)
#define OFF_VARS   (OFF_MEANS + S_LEN*BATCH*NMIX)
#define OFF_WTS    (OFF_VARS  + S_LEN*BATCH*NMIX)

// scratch layout in d_ws (byte offsets)
#define WS_XH    0            // f16  8 MB   (8192x512)
#define WS_W1T   (8u<<20)     // f16  512 KB (512x512, [n][k] TRANSPOSED)
#define WS_W2T   (9u<<20)     // f32  64 KB  (32x512 padded)
#define WS_HH    (10u<<20)    // f16  8 MB
#define WS_DM    (26u<<20)    // f32  320 KB delta-means, chain-major [b][k][s]

#define NX4     1048576       // X float4 count
#define CVT_BLOCKS (NX4/256)  // 4096
#define W1T_BLOCKS 64
#define W2T_BLOCKS 64

typedef float    f32x16 __attribute__((ext_vector_type(16)));
typedef float    f32x4v __attribute__((ext_vector_type(4)));
typedef _Float16 f16x8  __attribute__((ext_vector_type(8)));

__device__ __forceinline__ unsigned short f2h(float x) {
    union { _Float16 h; unsigned short u; } cv;
    cv.h = (_Float16)x;
    return cv.u;
}
__device__ __forceinline__ ushort4 cvt4(float4 v) {
    ushort4 o; o.x = f2h(v.x); o.y = f2h(v.y); o.z = f2h(v.z); o.w = f2h(v.w);
    return o;
}
__device__ __forceinline__ void nt_store4(float* p, float a, float b, float c, float d) {
    f32x4v v; v.x = a; v.y = b; v.z = c; v.w = d;
    __builtin_nontemporal_store(v, (f32x4v*)p);
}

// async global->LDS, 16 B per lane.  LDS dest = wave-uniform base + lane*16
// (intrinsic semantics); global source is per-lane.  Address-space casts via
// integer round-trip (CK's amd_direct_load_global_to_lds pattern).
typedef __attribute__((address_space(1))) const unsigned int ga_u32;
typedef __attribute__((address_space(3))) unsigned int ls_u32;
__device__ __forceinline__ void gload_lds16(const unsigned short* g, unsigned short* l) {
    __builtin_amdgcn_global_load_lds(
        (ga_u32*)(unsigned long long)(const void*)g,
        (ls_u32*)(unsigned int)(unsigned long long)(void*)l,
        16, 0, 0);
}

// ---------------------------------------------------------------------------
// Kernel 0: convert X -> f16; W1 -> f16 TRANSPOSED [n][k]; W2^T fp32.
// ---------------------------------------------------------------------------
__global__ __launch_bounds__(256) void convert_kernel(
    const float* __restrict__ X, const float* __restrict__ W1,
    const float* __restrict__ W2,
    unsigned short* __restrict__ Xh, unsigned short* __restrict__ W1T,
    float* __restrict__ W2T)
{
    const int bid = blockIdx.x;
    const int tid = threadIdx.x;
    if (bid < CVT_BLOCKS) {
        const int i4 = bid*256 + tid;
        ((ushort4*)Xh)[i4] = cvt4(((const float4*)X)[i4]);
    } else if (bid < CVT_BLOCKS + W1T_BLOCKS) {
        __shared__ unsigned short tile[64*68];
        const int b2 = bid - CVT_BLOCKS;
        const int k0 = (b2 >> 3) * 64, n0 = (b2 & 7) * 64;
        #pragma unroll
        for (int q = 0; q < 4; q++) {
            const int r = q*16 + (tid >> 4);
            const int c = (tid & 15) * 4;
            float4 v = *(const float4*)(W1 + (size_t)(k0+r)*DF + n0 + c);
            *(ushort4*)(tile + r*68 + c) = cvt4(v);
        }
        __syncthreads();
        #pragma unroll
        for (int q = 0; q < 4; q++) {
            const int n  = q*16 + (tid >> 4);
            const int kq = (tid & 15) * 4;
            ushort4 o;
            o.x = tile[(kq+0)*68 + n];
            o.y = tile[(kq+1)*68 + n];
            o.z = tile[(kq+2)*68 + n];
            o.w = tile[(kq+3)*68 + n];
            *(ushort4*)(W1T + (size_t)(n0+n)*DIN + k0 + kq) = o;
        }
    } else {
        const int idx = (bid - CVT_BLOCKS - W1T_BLOCKS)*256 + tid;
        if (idx < 512*32) {
            const int j = idx >> 9, k = idx & 511;
            W2T[idx] = (j < 30) ? W2[k*30 + j] : 0.f;
        }
    }
}

// ---------------------------------------------------------------------------
// Kernel 1: GEMM1, 128x128 tile / BK=64 / 256 threads (4 waves, each a 64x64
// quadrant as 2x2 32x32x16 MFMA).  Staging via global_load_lds width=16
// (m93->m97 ladder step: 517->874 TF on this structure).  Bank-conflict XOR
// swizzle is applied on the per-lane GLOBAL source granule ((l&7)^(l>>3)),
// so LDS dest stays linear as the intrinsic requires; physical granule p of
// row r holds logical k-granule p^(r&7), matching the (ac ^ szm) reads.
// ---------------------------------------------------------------------------
__global__ __launch_bounds__(256) void gemm1_kernel(
    const unsigned short* __restrict__ Xh, const unsigned short* __restrict__ W1T,
    const float* __restrict__ b1, unsigned short* __restrict__ Hh)
{
    __shared__ __align__(16) unsigned short As[128*64];   // 16 KB
    __shared__ __align__(16) unsigned short Bs[128*64];   // 16 KB
    const int row0 = (blockIdx.x >> 2) * 128;
    const int n0   = (blockIdx.x & 3)  * 128;
    const int tid  = threadIdx.x;
    const int lane = tid & 63, w = tid >> 6;
    const int wr2 = (w >> 1) * 64, wc2 = (w & 1) * 64;   // wave quadrant
    const int m  = lane & 31, g = lane >> 5;
    const int szm = (m & 7) << 3;

    // staging: issue q covers rows w*32 + q*8 .. +7; lane l -> row +(l>>3),
    // source k-granule (l&7)^(l>>3) (xor pre-swizzle), 16 B each.
    const int lr = lane >> 3;
    const int lc = ((lane & 7) ^ lr) * 8;
    const unsigned short* aS = Xh  + (size_t)(row0 + w*32 + lr)*DIN + lc;
    const unsigned short* bS = W1T + (size_t)(n0   + w*32 + lr)*DIN + lc;

    f32x16 acc00 = {}, acc01 = {}, acc10 = {}, acc11 = {};

    for (int kt = 0; kt < DIN; kt += 64) {
        #pragma unroll
        for (int q = 0; q < 4; q++) {
            gload_lds16(aS + (size_t)(q*8)*DIN + kt, As + (w*4 + q)*512);
            gload_lds16(bS + (size_t)(q*8)*DIN + kt, Bs + (w*4 + q)*512);
        }
        __syncthreads();   // drains vmcnt -> tile resident
        #pragma unroll
        for (int ks = 0; ks < 64; ks += 16) {
            const int ac = ks + g*8;
            f16x8 a0 = *(const f16x8*)(As + (wr2      + m)*64 + (ac ^ szm));
            f16x8 a1 = *(const f16x8*)(As + (wr2 + 32 + m)*64 + (ac ^ szm));
            f16x8 b0 = *(const f16x8*)(Bs + (wc2      + m)*64 + (ac ^ szm));
            f16x8 b1v= *(const f16x8*)(Bs + (wc2 + 32 + m)*64 + (ac ^ szm));
            acc00 = __builtin_amdgcn_mfma_f32_32x32x16_f16(a0, b0,  acc00, 0, 0, 0);
            acc01 = __builtin_amdgcn_mfma_f32_32x32x16_f16(a0, b1v, acc01, 0, 0, 0);
            acc10 = __builtin_amdgcn_mfma_f32_32x32x16_f16(a1, b0,  acc10, 0, 0, 0);
            acc11 = __builtin_amdgcn_mfma_f32_32x32x16_f16(a1, b1v, acc11, 0, 0, 0);
        }
        __syncthreads();   // all reads done before next overwrite
    }

    const int nc = n0 + wc2 + m;
    const float bb0 = b1[nc], bb1 = b1[nc + 32];
    #pragma unroll
    for (int r = 0; r < 16; r++) {
        const int rowloc = (r & 3) + 8*(r >> 2) + 4*g;
        const int rA = row0 + wr2 + rowloc;
        const int rB = rA + 32;
        float v;
        v = acc00[r] + bb0; v = v > 0.f ? v : 0.01f*v; Hh[(size_t)rA*DF + nc]      = f2h(v);
        v = acc01[r] + bb1; v = v > 0.f ? v : 0.01f*v; Hh[(size_t)rA*DF + nc + 32] = f2h(v);
        v = acc10[r] + bb0; v = v > 0.f ? v : 0.01f*v; Hh[(size_t)rB*DF + nc]      = f2h(v);
        v = acc11[r] + bb1; v = v > 0.f ? v : 0.01f*v; Hh[(size_t)rB*DF + nc + 32] = f2h(v);
    }
}

// ---------------------------------------------------------------------------
// Kernel 2: GEMM2 (8192x30, K=512); LDS-staged H, broadcast W2T reads.
// delta-means written chain-major [b][k][s] for the fused scan.
// ---------------------------------------------------------------------------
__global__ __launch_bounds__(256) void gemm2_kernel(
    const unsigned short* __restrict__ Hh, const float* __restrict__ W2T,
    const float* __restrict__ b2,
    float* __restrict__ dm_ws, float* __restrict__ dvars, float* __restrict__ dwts)
{
    __shared__ __align__(16) unsigned short Hs[32*520];
    const int tid = threadIdx.x;
    const int r0  = blockIdx.x * 32;
    {
        const uint4* src = (const uint4*)(Hh + (size_t)r0*DF);
        #pragma unroll
        for (int i = 0; i < 8; i++) {
            int u   = tid + i*256;
            int row = u >> 6;
            int col = (u & 63) * 8;
            *(uint4*)(Hs + row*520 + col) = src[u];
        }
    }
    __syncthreads();

    const int r  = tid & 31;
    const int j0 = tid >> 5;
    const unsigned short* hrow = Hs + r*520;
    float acc[4] = {0.f, 0.f, 0.f, 0.f};

    for (int k0 = 0; k0 < DF; k0 += 8) {
        union { uint4 u; _Float16 h[8]; } hv;
        hv.u = *(const uint4*)(hrow + k0);
        float wv[4][8];
        #pragma unroll
        for (int q = 0; q < 4; q++) {
            *(float4*)(wv[q])     = *(const float4*)(W2T + (size_t)(j0 + q*8)*DF + k0);
            *(float4*)(wv[q] + 4) = *(const float4*)(W2T + (size_t)(j0 + q*8)*DF + k0 + 4);
        }
        #pragma unroll
        for (int i = 0; i < 8; i++) {
            float hf = (float)hv.h[i];
            acc[0] = fmaf(hf, wv[0][i], acc[0]);
            acc[1] = fmaf(hf, wv[1][i], acc[1]);
            acc[2] = fmaf(hf, wv[2][i], acc[2]);
            acc[3] = fmaf(hf, wv[3][i], acc[3]);
        }
    }
    const int row = r0 + r;
    #pragma unroll
    for (int q = 0; q < 4; q++) {
        const int j = j0 + q*8;
        if (j >= 30) continue;
        float dot = acc[q] + b2[j];
        float sp  = fmaxf(dot, 0.f) + log1pf(__expf(-fabsf(dot)));
        if (j < 10) {
            const int bb = row & (BATCH-1), s = row >> 4;
            dm_ws[((size_t)bb*NMIX + j)*S_LEN + s] = sp * (1.f/25.f);
        }
        else if (j < 20)  dvars[row*NMIX + (j-10)] = fminf(fmaxf(sp, 0.01f), 100.f);
        else              dwts [row*NMIX + (j-20)] = sp;
    }
}

// ---------------------------------------------------------------------------
// Kernel 3: fused scan + means + attention weights + attended contexts.
// 256 threads (4 waves) — 512-thread blocks get a 56-VGPR cap here and spill.
// ---------------------------------------------------------------------------
__global__ __launch_bounds__(256) void fused_kernel(
    const float* __restrict__ dm_ws, const float* __restrict__ init_means,
    const float* __restrict__ vars_g, const float* __restrict__ wts_g,
    const float* __restrict__ ctx,
    float* __restrict__ means_out, float* __restrict__ attn_out,
    float* __restrict__ ctxout)
{
    __shared__ float mlds[320];
    __shared__ float vlds[320];
    __shared__ float wlds[320];
    __shared__ float redbuf[4];
    __shared__ __align__(16) unsigned short As[32*72];     //  4.5 KB
    __shared__ __align__(16) unsigned short Bs[256*72];    // 36.0 KB

    const int bid = blockIdx.x;
    const int b   = bid >> 4;          // batch
    const int s0  = (bid & 15) * 32;   // first row of tile
    const int tid = threadIdx.x;
    const int lane = tid & 63, w = tid >> 6;   // 4 waves
    const int m = lane & 31, g = lane >> 5;

    // ---- carry (parallel sum over [0,s0)) + 32-window scan, per chain ----
    for (int k = w; k < NMIX; k += 4) {
        const float* chain = dm_ws + ((size_t)b*NMIX + k)*S_LEN;
        float part = 0.f;
        for (int s = lane; s < s0; s += 64) part += chain[s];
        #pragma unroll
        for (int d = 32; d >= 1; d >>= 1) part += __shfl_xor(part, d, 64);
        const float carry = init_means[b*NMIX + k] + part;
        float v = (lane < 32) ? chain[s0 + lane] : 0.f;
        #pragma unroll
        for (int d = 1; d < 32; d <<= 1) {
            float t = __shfl_up(v, d, 64);
            if (lane >= d) v += t;
        }
        if (lane < 32) mlds[lane*NMIX + k] = carry + v;
    }
    for (int idx = tid; idx < 320; idx += 256) {
        const int s = idx / NMIX, k = idx - s*NMIX;
        const int row = (s0 + s)*BATCH + b;
        vlds[idx] = vars_g[row*NMIX + k];
        wlds[idx] = wts_g [row*NMIX + k];
    }
    __syncthreads();

    // ---- means output + local reach bound (no atomics) ----
    float reach = 0.f;
    for (int idx = tid; idx < 320; idx += 256) {
        const int s = idx / NMIX, k = idx - s*NMIX;
        means_out[((s0 + s)*BATCH + b)*NMIX + k] = mlds[idx];
        reach = fmaxf(reach, mlds[idx] + 4.8f * rsqrtf(vlds[idx]));
    }
    #pragma unroll
    for (int d = 32; d >= 1; d >>= 1) reach = fmaxf(reach, __shfl_xor(reach, d, 64));
    if (lane == 0) redbuf[w] = reach;
    __syncthreads();
    const float rmax = fmaxf(fmaxf(redbuf[0], redbuf[1]),
                             fmaxf(redbuf[2], redbuf[3]));
    const int kmax = min(NCHAR, (((int)rmax) + 64) & ~63);

    // ---- per-thread row params (row r fixed across chunks) ----
    const int r  = tid >> 3;       // 0..31
    const int c0 = (tid & 7) * 8;  // 8 chars per thread per 64-chunk
    float mr[NMIX], vr[NMIX], wr_[NMIX];
    #pragma unroll
    for (int k = 0; k < NMIX; k++) {
        mr[k]  = mlds[r*NMIX + k];
        vr[k]  = vlds[r*NMIX + k];
        wr_[k] = wlds[r*NMIX + k];
    }
    const size_t arow = (size_t)((s0 + r)*BATCH + b) * NCHAR;

    // ctx staging ids: thread covers (char-row tb, dctx seg dseg*64..+63)
    const int tb = tid & 63, dseg = tid >> 6;
    const float* cbase = ctx + (size_t)b*DCTX + dseg*64;

    f32x16 acc0 = {}, acc1 = {};
    for (int kt = 0; kt < kmax; kt += 64) {
        // attention weights for chars kt+c0 .. +7 of row r
        float o[8];
        #pragma unroll
        for (int i = 0; i < 8; i++) {
            const float t = (float)(kt + c0 + i);
            float sum = 0.f;
            #pragma unroll
            for (int k = 0; k < NMIX; k++) {
                float d = t - mr[k];
                sum += wr_[k] * __expf(-d*d*vr[k]);
            }
            o[i] = sum;
        }
        __syncthreads();   // previous chunk's MFMA reads done
        nt_store4(attn_out + arow + kt + c0,     o[0], o[1], o[2], o[3]);
        nt_store4(attn_out + arow + kt + c0 + 4, o[4], o[5], o[6], o[7]);
        {
            ushort4 h0, h1;
            h0.x = f2h(o[0]); h0.y = f2h(o[1]); h0.z = f2h(o[2]); h0.w = f2h(o[3]);
            h1.x = f2h(o[4]); h1.y = f2h(o[5]); h1.z = f2h(o[6]); h1.w = f2h(o[7]);
            *(ushort4*)(As + r*72 + c0)     = h0;
            *(ushort4*)(As + r*72 + c0 + 4) = h1;
        }
        {
            const float* p = cbase + (size_t)(kt + tb)*(BATCH*DCTX);
            #pragma unroll
            for (int e = 0; e < 4; e++) {
                float4 f0 = *(const float4*)(p + e*16);
                float4 f1 = *(const float4*)(p + e*16 + 4);
                float4 f2 = *(const float4*)(p + e*16 + 8);
                float4 f3 = *(const float4*)(p + e*16 + 12);
                ushort4 h0 = cvt4(f0), h1 = cvt4(f1), h2 = cvt4(f2), h3 = cvt4(f3);
                const int db = dseg*64 + e*16;
                Bs[(db + 0)*72 + tb] = h0.x;  Bs[(db + 1)*72 + tb] = h0.y;
                Bs[(db + 2)*72 + tb] = h0.z;  Bs[(db + 3)*72 + tb] = h0.w;
                Bs[(db + 4)*72 + tb] = h1.x;  Bs[(db + 5)*72 + tb] = h1.y;
                Bs[(db + 6)*72 + tb] = h1.z;  Bs[(db + 7)*72 + tb] = h1.w;
                Bs[(db + 8)*72 + tb] = h2.x;  Bs[(db + 9)*72 + tb] = h2.y;
                Bs[(db +10)*72 + tb] = h2.z;  Bs[(db +11)*72 + tb] = h2.w;
                Bs[(db +12)*72 + tb] = h3.x;  Bs[(db +13)*72 + tb] = h3.y;
                Bs[(db +14)*72 + tb] = h3.z;  Bs[(db +15)*72 + tb] = h3.w;
            }
        }
        __syncthreads();
        #pragma unroll
        for (int ks = 0; ks < 64; ks += 16) {
            f16x8 af  = *(const f16x8*)(As + m*72 + ks + g*8);
            f16x8 bf0 = *(const f16x8*)(Bs + (w*64 + m)*72      + ks + g*8);
            f16x8 bf1 = *(const f16x8*)(Bs + (w*64 + 32 + m)*72 + ks + g*8);
            acc0 = __builtin_amdgcn_mfma_f32_32x32x16_f16(af, bf0, acc0, 0, 0, 0);
            acc1 = __builtin_amdgcn_mfma_f32_32x32x16_f16(af, bf1, acc1, 0, 0, 0);
        }
    }
    // zero tail of attention output
    for (int t = kmax + c0; t < NCHAR; t += 64) {
        nt_store4(attn_out + arow + t,     0.f, 0.f, 0.f, 0.f);
        nt_store4(attn_out + arow + t + 4, 0.f, 0.f, 0.f, 0.f);
    }

    // attended-context epilogue: wave w owns dctx cols w*64+m and w*64+32+m
    #pragma unroll
    for (int rr = 0; rr < 16; rr++) {
        const int rowloc = (rr & 3) + 8*(rr >> 2) + 4*g;
        const int s = s0 + rowloc;
        float* op = ctxout + ((size_t)s*BATCH + b)*DCTX + w*64 + m;
        __builtin_nontemporal_store(acc0[rr], op);
        __builtin_nontemporal_store(acc1[rr], op + 32);
    }
}

// ---------------------------------------------------------------------------
extern "C" void kernel_launch(void* const* d_in, const int* in_sizes, int n_in,
                              void* d_out, int out_size, void* d_ws, size_t ws_size,
                              hipStream_t stream)
{
    const float* X     = (const float*)d_in[0];
    const float* ctx   = (const float*)d_in[1];
    const float* initm = (const float*)d_in[2];
    const float* W1    = (const float*)d_in[3];
    const float* b1    = (const float*)d_in[4];
    const float* W2    = (const float*)d_in[5];
    const float* b2    = (const float*)d_in[6];

    float* out      = (float*)d_out;
    float* out_ctx  = out + OFF_CTXOUT;
    float* out_attn = out + OFF_ATTN;
    float* out_mean = out + OFF_MEANS;
    float* out_var  = out + OFF_VARS;
    float* out_wts  = out + OFF_WTS;

    char* ws = (char*)d_ws;
    unsigned short* Xh   = (unsigned short*)(ws + WS_XH);
    unsigned short* W1T  = (unsigned short*)(ws + WS_W1T);
    float*          W2T  = (float*)         (ws + WS_W2T);
    unsigned short* Hh   = (unsigned short*)(ws + WS_HH);
    float*          dmws = (float*)         (ws + WS_DM);

    convert_kernel<<<CVT_BLOCKS + W1T_BLOCKS + W2T_BLOCKS, 256, 0, stream>>>(
        X, W1, W2, Xh, W1T, W2T);
    gemm1_kernel<<<(M_ROWS/128)*(DF/128), 256, 0, stream>>>(Xh, W1T, b1, Hh);
    gemm2_kernel<<<M_ROWS/32, 256, 0, stream>>>(Hh, W2T, b2, dmws, out_var, out_wts);
    fused_kernel<<<BATCH*16, 256, 0, stream>>>(dmws, initm, out_var, out_wts, ctx,
                                               out_mean, out_attn, out_ctx);
}